// Round 3
// baseline (55.394 us; speedup 1.0000x reference)
//
#include <hip/hip_runtime.h>
#include <hip/hip_bf16.h>

typedef __attribute__((ext_vector_type(8))) short short8;
typedef __attribute__((ext_vector_type(4))) float f32x4;

#define NTOK 4096
#define DIN  1024
#define DOUT 1024
#define KTOT 1152   // 1024 (W) + 128 (LoRA)
#define XLD  1152
#define TLD  192

__device__ __forceinline__ unsigned short f2bf(float f) {
    __hip_bfloat16 h = __float2bfloat16(f);
    return __builtin_bit_cast(unsigned short, h);
}

__device__ __forceinline__ void gload16(const void* g, void* l) {
    __builtin_amdgcn_global_load_lds((const __attribute__((address_space(1))) void*)g,
                                     (__attribute__((address_space(3))) void*)l, 16, 0, 0);
}

__device__ __forceinline__ uint4 pack8(const float* s) {
    float4 v0 = *(const float4*)s, v1 = *(const float4*)(s + 4);
    union { unsigned short u[8]; uint4 q; } pk;
    pk.u[0] = f2bf(v0.x); pk.u[1] = f2bf(v0.y); pk.u[2] = f2bf(v0.z); pk.u[3] = f2bf(v0.w);
    pk.u[4] = f2bf(v1.x); pk.u[5] = f2bf(v1.y); pk.u[6] = f2bf(v1.z); pk.u[7] = f2bf(v1.w);
    return pk.q;
}

// ---- x (4096x1024 f32) -> Xcat[:, 0:1024] bf16 (LD 1152). grid 2048x256 ----
__global__ __launch_bounds__(256) void k_cvtx(const float* __restrict__ x,
                                              __hip_bfloat16* __restrict__ Xcat) {
    int idx = blockIdx.x * 256 + threadIdx.x;      // one 8-elem group each
    int n = idx >> 7, g = idx & 127;
    uint4 q = pack8(x + (size_t)n * DIN + g * 8);
    *(uint4*)(Xcat + (size_t)n * XLD + g * 8) = q;
}

// ---- Ucat (192x1024 bf16) = [lora_U(128); gate_w(8); zeros]. grid 96x256 ---
__global__ __launch_bounds__(256) void k_cvtu(const float* __restrict__ lora_U,
                                              const float* __restrict__ gate_w,
                                              __hip_bfloat16* __restrict__ Ucat) {
    int idx = blockIdx.x * 256 + threadIdx.x;
    int r = idx >> 7, g = idx & 127;
    uint4 q = make_uint4(0u, 0u, 0u, 0u);
    if (r < 128)      q = pack8(lora_U + (size_t)r * DIN + g * 8);
    else if (r < 136) q = pack8(gate_w + (size_t)(r - 128) * DIN + g * 8);
    *(uint4*)(Ucat + (size_t)r * DIN + g * 8) = q;
}

// ---- Wcat (1024x1152 bf16) = [weight | V2], V2[o][e*16+r]=lora_V[e][o][r] --
// grid 1024 x 256 (144 active threads)
__global__ __launch_bounds__(256) void k_cvtw(const float* __restrict__ w,
                                              const float* __restrict__ lora_V,
                                              __hip_bfloat16* __restrict__ Wcat) {
    int o = blockIdx.x, g = threadIdx.x;
    if (g >= 144) return;
    const float* s;
    if (g < 128) s = w + (size_t)o * DIN + g * 8;
    else {
        int idx0 = (g - 128) * 8;                 // 0..127 within LoRA cols
        int e = idx0 >> 4, r = idx0 & 15;         // r in {0,8}
        s = lora_V + (size_t)e * (DOUT * 16) + (size_t)o * 16 + r;
    }
    *(uint4*)(Wcat + (size_t)o * KTOT + g * 8) = pack8(s);
}

// ---- softmax gate + coef: Xcat[n][1024+j] = bf16(gate[n][j>>4]*T[n][j]/16) -
// grid 2048 x 256 (2 tokens/block)
__global__ __launch_bounds__(256) void k_coef(const float* __restrict__ T,
                                              __hip_bfloat16* __restrict__ Xcat) {
    int n = blockIdx.x * 2 + (threadIdx.x >> 7);
    int j = threadIdx.x & 127;
    const float* Tr = T + (size_t)n * TLD;
    float l[8];
#pragma unroll
    for (int e = 0; e < 8; ++e) l[e] = Tr[128 + e];
    float m = l[0];
#pragma unroll
    for (int e = 1; e < 8; ++e) m = fmaxf(m, l[e]);
    float s = 0.f;
#pragma unroll
    for (int e = 0; e < 8; ++e) s += __expf(l[e] - m);
    float g = __expf(l[j >> 4] - m) / s;
    Xcat[(size_t)n * XLD + 1024 + j] = __float2bfloat16(g * Tr[j] * 0.0625f);
}

// ---- MFMA GEMM: out[M x ...] = A(rows x lda) @ B(cols x ldb)^T -------------
// BM=128, BN=64, BK=64, 256 threads = 4 waves (2x2), wave tile 64x32.
// LDS XOR-swizzle slot^=(row&7) applied on BOTH the pre-swizzled global src
// (global_load_lds writes linearly) and the ds_read side.
__global__ __launch_bounds__(256) void k_gemm(const __hip_bfloat16* __restrict__ A, int lda,
                                              const __hip_bfloat16* __restrict__ B, int ldb,
                                              float* __restrict__ out, int ldo,
                                              int nk) {
    __shared__ __hip_bfloat16 Asm[128 * 64];
    __shared__ __hip_bfloat16 Bsm[64 * 64];
    const int t = threadIdx.x, lane = t & 63, wid = t >> 6;
    const int wr = wid >> 1, wc = wid & 1;
    const int row0 = blockIdx.x * 128, col0 = blockIdx.y * 64;
    const int l7 = lane & 7, l8 = lane >> 3, l15 = lane & 15, l16 = lane >> 4;
    const int scol = ((l7 ^ l8) << 3);             // pre-swizzled global col

    f32x4 zf = {0.f, 0.f, 0.f, 0.f};
    f32x4 acc[4][2];
#pragma unroll
    for (int m = 0; m < 4; ++m)
#pragma unroll
        for (int n = 0; n < 2; ++n) acc[m][n] = zf;

    int aoff[4], boff[2], sw[2];
#pragma unroll
    for (int m = 0; m < 4; ++m) aoff[m] = (wr * 64 + m * 16 + l15) * 128;   // bytes
#pragma unroll
    for (int n = 0; n < 2; ++n) boff[n] = (wc * 32 + n * 16 + l15) * 128;
#pragma unroll
    for (int ks = 0; ks < 2; ++ks) sw[ks] = (((ks * 4 + l16) ^ l7) << 4);

    for (int kt = 0; kt < nk; ++kt) {
        const int k0 = kt << 6;
#pragma unroll
        for (int i = 0; i < 4; ++i) {
            int ci = wid * 4 + i;                  // wave-uniform chunk id
            gload16(A + (size_t)(row0 + ci * 8 + l8) * lda + k0 + scol,
                    (char*)Asm + ci * 1024);
        }
#pragma unroll
        for (int i = 0; i < 2; ++i) {
            int cj = wid * 2 + i;
            gload16(B + (size_t)(col0 + cj * 8 + l8) * ldb + k0 + scol,
                    (char*)Bsm + cj * 1024);
        }
        __syncthreads();
#pragma unroll
        for (int ks = 0; ks < 2; ++ks) {
            short8 af[4], bf[2];
#pragma unroll
            for (int m = 0; m < 4; ++m)
                af[m] = *(const short8*)((const char*)Asm + aoff[m] + sw[ks]);
#pragma unroll
            for (int n = 0; n < 2; ++n)
                bf[n] = *(const short8*)((const char*)Bsm + boff[n] + sw[ks]);
#pragma unroll
            for (int m = 0; m < 4; ++m)
#pragma unroll
                for (int n = 0; n < 2; ++n)
                    acc[m][n] = __builtin_amdgcn_mfma_f32_16x16x32_bf16(af[m], bf[n], acc[m][n], 0, 0, 0);
        }
        __syncthreads();
    }

#pragma unroll
    for (int m = 0; m < 4; ++m)
#pragma unroll
        for (int n = 0; n < 2; ++n)
#pragma unroll
            for (int j = 0; j < 4; ++j)
                out[(size_t)(row0 + wr * 64 + m * 16 + l16 * 4 + j) * ldo
                    + col0 + wc * 32 + n * 16 + l15] = acc[m][n][j];
}

extern "C" void kernel_launch(void* const* d_in, const int* in_sizes, int n_in,
                              void* d_out, int out_size, void* d_ws, size_t ws_size,
                              hipStream_t stream) {
    const float* x      = (const float*)d_in[0];   // (4,1024,1024)
    const float* weight = (const float*)d_in[1];   // (1024,1024)
    const float* gate_w = (const float*)d_in[2];   // (8,1024)
    const float* lora_U = (const float*)d_in[3];   // (8,16,1024)
    const float* lora_V = (const float*)d_in[4];   // (8,1024,16)
    float* out = (float*)d_out;

    char* ws = (char*)d_ws;
    float*          T    = (float*)ws;                          // 4096x192 f32   (3.15 MB)
    __hip_bfloat16* Xcat = (__hip_bfloat16*)(ws + 3145728);     // 4096x1152 bf16 (9.44 MB)
    __hip_bfloat16* Ucat = (__hip_bfloat16*)(ws + 3145728 + 9437184);            // 192x1024
    __hip_bfloat16* Wcat = (__hip_bfloat16*)(ws + 3145728 + 9437184 + 393216);   // 1024x1152

    k_cvtx<<<2048, 256, 0, stream>>>(x, Xcat);
    k_cvtu<<<96,   256, 0, stream>>>(lora_U, gate_w, Ucat);
    k_cvtw<<<1024, 256, 0, stream>>>(weight, lora_V, Wcat);
    // T = Xcat[:, :1024] @ Ucat^T   (K=1024, 16 steps), grid (32, 3)
    k_gemm<<<dim3(32, 3),  256, 0, stream>>>(Xcat, XLD, Ucat, DIN,  T,   TLD,  16);
    k_coef<<<2048, 256, 0, stream>>>(T, Xcat);
    // out = Xcat @ Wcat^T           (K=1152, 18 steps), grid (32, 16)
    k_gemm<<<dim3(32, 16), 256, 0, stream>>>(Xcat, XLD, Wcat, KTOT, out, DOUT, 18);
}

// Round 6
// 52.988 us; speedup vs baseline: 1.0454x; 1.0454x over previous
//
#include <hip/hip_runtime.h>
#include <hip/hip_bf16.h>

typedef __attribute__((ext_vector_type(8))) short short8;
typedef __attribute__((ext_vector_type(4))) float f32x4;

#define NTOK 4096
#define DIN  1024
#define DOUT 1024
#define KTOT 1152   // 1024 (W) + 128 (LoRA)
#define XLD  1152
#define TLDS 200    // Tsm leading dim (f32)

__device__ __forceinline__ unsigned short f2bf(float f) {
    __hip_bfloat16 h = __float2bfloat16(f);
    return __builtin_bit_cast(unsigned short, h);
}

__device__ __forceinline__ void gload16(const void* g, void* l) {
    __builtin_amdgcn_global_load_lds((const __attribute__((address_space(1))) void*)g,
                                     (__attribute__((address_space(3))) void*)l, 16, 0, 0);
}

__device__ __forceinline__ uint4 pack8(const float* s) {
    float4 v0 = *(const float4*)s, v1 = *(const float4*)(s + 4);
    union { unsigned short u[8]; uint4 q; } pk;
    pk.u[0] = f2bf(v0.x); pk.u[1] = f2bf(v0.y); pk.u[2] = f2bf(v0.z); pk.u[3] = f2bf(v0.w);
    pk.u[4] = f2bf(v1.x); pk.u[5] = f2bf(v1.y); pk.u[6] = f2bf(v1.z); pk.u[7] = f2bf(v1.w);
    return pk.q;
}

// ---- weight prep: Ucat (192x1024) = [lora_U;gate_w;0], Wcat (1024x1152) = [W|V2]
// grid 96 + 576 = 672 blocks x 256
__global__ __launch_bounds__(256) void k_cvtuw(const float* __restrict__ lora_U,
                                               const float* __restrict__ gate_w,
                                               const float* __restrict__ w,
                                               const float* __restrict__ lora_V,
                                               __hip_bfloat16* __restrict__ Ucat,
                                               __hip_bfloat16* __restrict__ Wcat) {
    int b = blockIdx.x;
    if (b < 96) {
        int idx = b * 256 + threadIdx.x;          // 192 rows x 128 groups
        int r = idx >> 7, g = idx & 127;
        uint4 q = make_uint4(0u, 0u, 0u, 0u);
        if (r < 128)      q = pack8(lora_U + (size_t)r * DIN + g * 8);
        else if (r < 136) q = pack8(gate_w + (size_t)(r - 128) * DIN + g * 8);
        *(uint4*)(Ucat + (size_t)r * DIN + g * 8) = q;
    } else {
        int idx = (b - 96) * 256 + threadIdx.x;   // 1024 rows x 144 groups
        int o = idx / 144, g = idx - o * 144;
        const float* s;
        if (g < 128) s = w + (size_t)o * DIN + g * 8;
        else {
            int i0 = (g - 128) * 8;               // 0..127 in LoRA cols
            int e = i0 >> 4, r = i0 & 15;         // r in {0,8}
            s = lora_V + (size_t)e * (DOUT * 16) + (size_t)o * 16 + r;
        }
        *(uint4*)(Wcat + (size_t)o * KTOT + g * 8) = pack8(s);
    }
}

// ---- GEMM1 fused: T = x @ Ucat^T (K=1024), softmax gate, coef -> Xcat ------
// Also converts x -> Xcat[:, :1024] bf16 as a side effect of A staging.
// BM=32, BN=192, BK=64, 256 threads = 4 waves (2x2), wave tile 16x96. grid 128.
__global__ __launch_bounds__(256) void k_gemm1f(const float* __restrict__ x,
                                                const __hip_bfloat16* __restrict__ Ucat,
                                                __hip_bfloat16* __restrict__ Xcat) {
    __shared__ char smem[28672];                   // Asm 4KB + Bsm 24KB; Tsm 25.6KB reuse
    __hip_bfloat16* Asm = (__hip_bfloat16*)smem;
    __hip_bfloat16* Bsm = (__hip_bfloat16*)(smem + 4096);
    float (*Tsm)[TLDS] = (float(*)[TLDS])smem;

    const int t = threadIdx.x, lane = t & 63, wid = t >> 6;
    const int wr = wid >> 1, wc = wid & 1;
    const int row0 = blockIdx.x * 32;
    const int l7 = lane & 7, l8 = lane >> 3, l15 = lane & 15, l16 = lane >> 4;
    const int scol = ((l7 ^ l8) << 3);             // pre-swizzled global col (B)

    f32x4 acc[6];
#pragma unroll
    for (int n = 0; n < 6; ++n) acc[n] = (f32x4){0.f, 0.f, 0.f, 0.f};

    const int ar = t >> 3;                         // A-staging row 0..31
    const int ac8 = (t & 7) * 8;                   // A-staging col group
    const int abyte = ar * 128 + (((t & 7) ^ (ar & 7)) << 4);   // swizzled LDS slot

    int boff[6];
#pragma unroll
    for (int n = 0; n < 6; ++n) boff[n] = (wc * 96 + n * 16 + l15) * 128;
    const int aoff = (wr * 16 + l15) * 128;
    int sw[2];
#pragma unroll
    for (int ks = 0; ks < 2; ++ks) sw[ks] = (((ks * 4 + l16) ^ l7) << 4);

    for (int kt = 0; kt < 16; ++kt) {
        const int k0 = kt << 6;
        // A: x f32 -> bf16 regs -> swizzled ds_write + side-store to Xcat
        uint4 q = pack8(x + (size_t)(row0 + ar) * DIN + k0 + ac8);
        *(uint4*)((char*)Asm + abyte) = q;
        *(uint4*)(Xcat + (size_t)(row0 + ar) * XLD + k0 + ac8) = q;
        // B: Ucat bf16 via global_load_lds, pre-swizzled source
#pragma unroll
        for (int i = 0; i < 6; ++i) {
            int cj = wid * 6 + i;
            gload16(Ucat + (size_t)(cj * 8 + l8) * DIN + k0 + scol,
                    (char*)Bsm + cj * 1024);
        }
        __syncthreads();
#pragma unroll
        for (int ks = 0; ks < 2; ++ks) {
            short8 af = *(const short8*)((const char*)Asm + aoff + sw[ks]);
#pragma unroll
            for (int n = 0; n < 6; ++n) {
                short8 bf = *(const short8*)((const char*)Bsm + boff[n] + sw[ks]);
                acc[n] = __builtin_amdgcn_mfma_f32_16x16x32_bf16(af, bf, acc[n], 0, 0, 0);
            }
        }
        __syncthreads();
    }

    // acc -> Tsm (f32), C/D mapping col=lane&15, row=(lane>>4)*4+j
#pragma unroll
    for (int n = 0; n < 6; ++n)
#pragma unroll
        for (int j = 0; j < 4; ++j)
            Tsm[wr * 16 + l16 * 4 + j][wc * 96 + n * 16 + l15] = acc[n][j];
    __syncthreads();

    // softmax + coef: 8 threads per token, thread owns expert e = t&7 (16 cols)
    {
        const int tok = t >> 3, e = t & 7;
        float l[8];
#pragma unroll
        for (int i = 0; i < 8; ++i) l[i] = Tsm[tok][128 + i];
        float m = l[0];
#pragma unroll
        for (int i = 1; i < 8; ++i) m = fmaxf(m, l[i]);
        float s = 0.f;
#pragma unroll
        for (int i = 0; i < 8; ++i) s += __expf(l[i] - m);
        const float g = __expf(l[e] - m) / s * 0.0625f;   // gate * 1/R
        union { unsigned short u[16]; uint4 q[2]; } pk;
#pragma unroll
        for (int jj = 0; jj < 16; ++jj) pk.u[jj] = f2bf(g * Tsm[tok][e * 16 + jj]);
        uint4* dst = (uint4*)(Xcat + (size_t)(row0 + tok) * XLD + 1024 + e * 16);
        dst[0] = pk.q[0]; dst[1] = pk.q[1];
    }
}

// ---- GEMM2: out = Xcat @ Wcat^T (K=1152) — unchanged proven kernel ---------
// BM=128, BN=64, BK=64, 256 threads = 4 waves (2x2), wave tile 64x32.
__global__ __launch_bounds__(256) void k_gemm(const __hip_bfloat16* __restrict__ A, int lda,
                                              const __hip_bfloat16* __restrict__ B, int ldb,
                                              float* __restrict__ out, int ldo,
                                              int nk) {
    __shared__ __hip_bfloat16 Asm[128 * 64];
    __shared__ __hip_bfloat16 Bsm[64 * 64];
    const int t = threadIdx.x, lane = t & 63, wid = t >> 6;
    const int wr = wid >> 1, wc = wid & 1;
    const int row0 = blockIdx.x * 128, col0 = blockIdx.y * 64;
    const int l7 = lane & 7, l8 = lane >> 3, l15 = lane & 15, l16 = lane >> 4;
    const int scol = ((l7 ^ l8) << 3);

    f32x4 zf = {0.f, 0.f, 0.f, 0.f};
    f32x4 acc[4][2];
#pragma unroll
    for (int m = 0; m < 4; ++m)
#pragma unroll
        for (int n = 0; n < 2; ++n) acc[m][n] = zf;

    int aoff[4], boff[2], sw[2];
#pragma unroll
    for (int m = 0; m < 4; ++m) aoff[m] = (wr * 64 + m * 16 + l15) * 128;
#pragma unroll
    for (int n = 0; n < 2; ++n) boff[n] = (wc * 32 + n * 16 + l15) * 128;
#pragma unroll
    for (int ks = 0; ks < 2; ++ks) sw[ks] = (((ks * 4 + l16) ^ l7) << 4);

    for (int kt = 0; kt < nk; ++kt) {
        const int k0 = kt << 6;
#pragma unroll
        for (int i = 0; i < 4; ++i) {
            int ci = wid * 4 + i;
            gload16(A + (size_t)(row0 + ci * 8 + l8) * lda + k0 + scol,
                    (char*)Asm + ci * 1024);
        }
#pragma unroll
        for (int i = 0; i < 2; ++i) {
            int cj = wid * 2 + i;
            gload16(B + (size_t)(col0 + cj * 8 + l8) * ldb + k0 + scol,
                    (char*)Bsm + cj * 1024);
        }
        __syncthreads();
#pragma unroll
        for (int ks = 0; ks < 2; ++ks) {
            short8 af[4], bf[2];
#pragma unroll
            for (int m = 0; m < 4; ++m)
                af[m] = *(const short8*)((const char*)Asm + aoff[m] + sw[ks]);
#pragma unroll
            for (int n = 0; n < 2; ++n)
                bf[n] = *(const short8*)((const char*)Bsm + boff[n] + sw[ks]);
#pragma unroll
            for (int m = 0; m < 4; ++m)
#pragma unroll
                for (int n = 0; n < 2; ++n)
                    acc[m][n] = __builtin_amdgcn_mfma_f32_16x16x32_bf16(af[m], bf[n], acc[m][n], 0, 0, 0);
        }
        __syncthreads();
    }

#pragma unroll
    for (int m = 0; m < 4; ++m)
#pragma unroll
        for (int n = 0; n < 2; ++n)
#pragma unroll
            for (int j = 0; j < 4; ++j)
                out[(size_t)(row0 + wr * 64 + m * 16 + l16 * 4 + j) * ldo
                    + col0 + wc * 32 + n * 16 + l15] = acc[m][n][j];
}

extern "C" void kernel_launch(void* const* d_in, const int* in_sizes, int n_in,
                              void* d_out, int out_size, void* d_ws, size_t ws_size,
                              hipStream_t stream) {
    const float* x      = (const float*)d_in[0];   // (4,1024,1024)
    const float* weight = (const float*)d_in[1];   // (1024,1024)
    const float* gate_w = (const float*)d_in[2];   // (8,1024)
    const float* lora_U = (const float*)d_in[3];   // (8,16,1024)
    const float* lora_V = (const float*)d_in[4];   // (8,1024,16)
    float* out = (float*)d_out;

    char* ws = (char*)d_ws;
    __hip_bfloat16* Xcat = (__hip_bfloat16*)ws;                        // 4096x1152 (9.44 MB)
    __hip_bfloat16* Ucat = (__hip_bfloat16*)(ws + 9437184);            // 192x1024  (0.39 MB)
    __hip_bfloat16* Wcat = (__hip_bfloat16*)(ws + 9437184 + 393216);   // 1024x1152 (2.36 MB)

    k_cvtuw<<<672, 256, 0, stream>>>(lora_U, gate_w, weight, lora_V, Ucat, Wcat);
    k_gemm1f<<<128, 256, 0, stream>>>(x, Ucat, Xcat);
    // out = Xcat @ Wcat^T (K=1152, 18 steps), grid (32, 16)
    k_gemm<<<dim3(32, 16), 256, 0, stream>>>(Xcat, XLD, Wcat, KTOT, out, DOUT, 18);
}

// Round 8
// 43.740 us; speedup vs baseline: 1.2664x; 1.2114x over previous
//
#include <hip/hip_runtime.h>
#include <hip/hip_bf16.h>

typedef __attribute__((ext_vector_type(8))) short short8;
typedef __attribute__((ext_vector_type(4))) float f32x4;

#define NTOK 4096
#define DIN  1024
#define DOUT 1024
#define KTOT 1152   // 1024 (W) + 128 (LoRA)
#define XLD  1152
#define TLDS 200    // Tsm leading dim (f32)

__device__ __forceinline__ unsigned short f2bf(float f) {
    __hip_bfloat16 h = __float2bfloat16(f);
    return __builtin_bit_cast(unsigned short, h);
}

__device__ __forceinline__ void gload16(const void* g, void* l) {
    __builtin_amdgcn_global_load_lds((const __attribute__((address_space(1))) void*)g,
                                     (__attribute__((address_space(3))) void*)l, 16, 0, 0);
}

__device__ __forceinline__ uint4 pack8(const float* s) {
    float4 v0 = *(const float4*)s, v1 = *(const float4*)(s + 4);
    union { unsigned short u[8]; uint4 q; } pk;
    pk.u[0] = f2bf(v0.x); pk.u[1] = f2bf(v0.y); pk.u[2] = f2bf(v0.z); pk.u[3] = f2bf(v0.w);
    pk.u[4] = f2bf(v1.x); pk.u[5] = f2bf(v1.y); pk.u[6] = f2bf(v1.z); pk.u[7] = f2bf(v1.w);
    return pk.q;
}

// ---- weight prep: Ucat (192x1024) = [lora_U;gate_w;0], Wcat (1024x1152) = [W|V2]
__global__ __launch_bounds__(256) void k_cvtuw(const float* __restrict__ lora_U,
                                               const float* __restrict__ gate_w,
                                               const float* __restrict__ w,
                                               const float* __restrict__ lora_V,
                                               __hip_bfloat16* __restrict__ Ucat,
                                               __hip_bfloat16* __restrict__ Wcat) {
    int b = blockIdx.x;
    if (b < 96) {
        int idx = b * 256 + threadIdx.x;          // 192 rows x 128 groups
        int r = idx >> 7, g = idx & 127;
        uint4 q = make_uint4(0u, 0u, 0u, 0u);
        if (r < 128)      q = pack8(lora_U + (size_t)r * DIN + g * 8);
        else if (r < 136) q = pack8(gate_w + (size_t)(r - 128) * DIN + g * 8);
        *(uint4*)(Ucat + (size_t)r * DIN + g * 8) = q;
    } else {
        int idx = (b - 96) * 256 + threadIdx.x;   // 1024 rows x 144 groups
        int o = idx / 144, g = idx - o * 144;
        const float* s;
        if (g < 128) s = w + (size_t)o * DIN + g * 8;
        else {
            int i0 = (g - 128) * 8;               // 0..127 in LoRA cols
            int e = i0 >> 4, r = i0 & 15;         // r in {0,8}
            s = lora_V + (size_t)e * (DOUT * 16) + (size_t)o * 16 + r;
        }
        *(uint4*)(Wcat + (size_t)o * KTOT + g * 8) = pack8(s);
    }
}

// ---- GEMM1 fused: T = x @ Ucat^T (K=1024), softmax gate, coef -> Xcat ------
// BM=16, BN=192, BK=64, 256 threads = 4 waves, wave tile 16x48. grid 256.
__global__ __launch_bounds__(256) void k_gemm1f(const float* __restrict__ x,
                                                const __hip_bfloat16* __restrict__ Ucat,
                                                __hip_bfloat16* __restrict__ Xcat) {
    __shared__ char smem[28672];                   // Asm 2KB + Bsm 24KB; Tsm 12.8KB reuse
    __hip_bfloat16* Asm = (__hip_bfloat16*)smem;
    __hip_bfloat16* Bsm = (__hip_bfloat16*)(smem + 2048);
    float (*Tsm)[TLDS] = (float(*)[TLDS])smem;

    const int t = threadIdx.x, lane = t & 63, wid = t >> 6;
    const int row0 = blockIdx.x * 16;
    const int l7 = lane & 7, l8 = lane >> 3, l15 = lane & 15, l16 = lane >> 4;
    const int scol = ((l7 ^ l8) << 3);             // pre-swizzled global col (B)

    f32x4 acc[3];
#pragma unroll
    for (int n = 0; n < 3; ++n) acc[n] = (f32x4){0.f, 0.f, 0.f, 0.f};

    const int ar = (t & 127) >> 3;                 // A-staging row 0..15
    const int ac8 = (t & 7) * 8;                   // A-staging col group
    const int abyte = ar * 128 + (((t & 7) ^ (ar & 7)) << 4);   // swizzled LDS slot

    int boff[3];
#pragma unroll
    for (int n = 0; n < 3; ++n) boff[n] = (wid * 48 + n * 16 + l15) * 128;
    const int aoff = l15 * 128;
    int sw[2];
#pragma unroll
    for (int ks = 0; ks < 2; ++ks) sw[ks] = (((ks * 4 + l16) ^ l7) << 4);

    for (int kt = 0; kt < 16; ++kt) {
        const int k0 = kt << 6;
        // A: x f32 -> bf16 regs -> swizzled ds_write + side-store to Xcat (t<128)
        if (t < 128) {
            uint4 q = pack8(x + (size_t)(row0 + ar) * DIN + k0 + ac8);
            *(uint4*)((char*)Asm + abyte) = q;
            *(uint4*)(Xcat + (size_t)(row0 + ar) * XLD + k0 + ac8) = q;
        }
        // B: Ucat bf16 via global_load_lds, pre-swizzled source (24 chunks)
#pragma unroll
        for (int i = 0; i < 6; ++i) {
            int cj = wid * 6 + i;
            gload16(Ucat + (size_t)(cj * 8 + l8) * DIN + k0 + scol,
                    (char*)Bsm + cj * 1024);
        }
        __syncthreads();
#pragma unroll
        for (int ks = 0; ks < 2; ++ks) {
            short8 af = *(const short8*)((const char*)Asm + aoff + sw[ks]);
#pragma unroll
            for (int n = 0; n < 3; ++n) {
                short8 bf = *(const short8*)((const char*)Bsm + boff[n] + sw[ks]);
                acc[n] = __builtin_amdgcn_mfma_f32_16x16x32_bf16(af, bf, acc[n], 0, 0, 0);
            }
        }
        __syncthreads();
    }

    // acc -> Tsm (f32), C/D mapping col=lane&15, row=(lane>>4)*4+j
#pragma unroll
    for (int n = 0; n < 3; ++n)
#pragma unroll
        for (int j = 0; j < 4; ++j)
            Tsm[l16 * 4 + j][wid * 48 + n * 16 + l15] = acc[n][j];
    __syncthreads();

    // softmax + coef: 8 threads per token (16 tokens x 8 experts = 128 threads)
    if (t < 128) {
        const int tok = t >> 3, e = t & 7;
        float l[8];
#pragma unroll
        for (int i = 0; i < 8; ++i) l[i] = Tsm[tok][128 + i];
        float m = l[0];
#pragma unroll
        for (int i = 1; i < 8; ++i) m = fmaxf(m, l[i]);
        float s = 0.f;
#pragma unroll
        for (int i = 0; i < 8; ++i) s += __expf(l[i] - m);
        const float g = __expf(l[e] - m) / s * 0.0625f;   // gate * 1/R
        union { unsigned short u[16]; uint4 q[2]; } pk;
#pragma unroll
        for (int jj = 0; jj < 16; ++jj) pk.u[jj] = f2bf(g * Tsm[tok][e * 16 + jj]);
        uint4* dst = (uint4*)(Xcat + (size_t)(row0 + tok) * XLD + 1024 + e * 16);
        dst[0] = pk.q[0]; dst[1] = pk.q[1];
    }
}

// ---- GEMM2: out = Xcat @ Wcat^T (K=1152) -----------------------------------
// BM=BN=64, BK=64, 256 threads = 4 waves (2x2), wave tile 32x32.
// Grid 1024 linear, XCD-swizzled: xcd=b&7 owns row-tiles xcd*8..+7 for all
// col-tiles -> per-XCD L2 keeps its Xcat slice (1.2MB) + Wcat (2.4MB).
__global__ __launch_bounds__(256) void k_gemm2(const __hip_bfloat16* __restrict__ A,
                                               const __hip_bfloat16* __restrict__ B,
                                               float* __restrict__ out) {
    __shared__ __hip_bfloat16 Asm[64 * 64];
    __shared__ __hip_bfloat16 Bsm[64 * 64];
    const int b = blockIdx.x;
    const int xcd = b & 7, j = b >> 3;
    const int bx = xcd * 8 + (j & 7), by = j >> 3;
    const int row0 = bx * 64, col0 = by * 64;

    const int t = threadIdx.x, lane = t & 63, wid = t >> 6;
    const int wr = wid >> 1, wc = wid & 1;
    const int l7 = lane & 7, l8 = lane >> 3, l15 = lane & 15, l16 = lane >> 4;
    const int scol = ((l7 ^ l8) << 3);

    f32x4 zf = {0.f, 0.f, 0.f, 0.f};
    f32x4 acc[2][2];
#pragma unroll
    for (int m = 0; m < 2; ++m)
#pragma unroll
        for (int n = 0; n < 2; ++n) acc[m][n] = zf;

    int aoff[2], boff[2], sw[2];
#pragma unroll
    for (int m = 0; m < 2; ++m) aoff[m] = (wr * 32 + m * 16 + l15) * 128;
#pragma unroll
    for (int n = 0; n < 2; ++n) boff[n] = (wc * 32 + n * 16 + l15) * 128;
#pragma unroll
    for (int ks = 0; ks < 2; ++ks) sw[ks] = (((ks * 4 + l16) ^ l7) << 4);

    for (int kt = 0; kt < 18; ++kt) {
        const int k0 = kt << 6;
#pragma unroll
        for (int i = 0; i < 2; ++i) {
            int ci = wid * 2 + i;                  // 8 chunks of 8 rows
            gload16(A + (size_t)(row0 + ci * 8 + l8) * XLD + k0 + scol,
                    (char*)Asm + ci * 1024);
            gload16(B + (size_t)(col0 + ci * 8 + l8) * KTOT + k0 + scol,
                    (char*)Bsm + ci * 1024);
        }
        __syncthreads();
#pragma unroll
        for (int ks = 0; ks < 2; ++ks) {
            short8 af[2], bf[2];
#pragma unroll
            for (int m = 0; m < 2; ++m)
                af[m] = *(const short8*)((const char*)Asm + aoff[m] + sw[ks]);
#pragma unroll
            for (int n = 0; n < 2; ++n)
                bf[n] = *(const short8*)((const char*)Bsm + boff[n] + sw[ks]);
#pragma unroll
            for (int m = 0; m < 2; ++m)
#pragma unroll
                for (int n = 0; n < 2; ++n)
                    acc[m][n] = __builtin_amdgcn_mfma_f32_16x16x32_bf16(af[m], bf[n], acc[m][n], 0, 0, 0);
        }
        __syncthreads();
    }

#pragma unroll
    for (int m = 0; m < 2; ++m)
#pragma unroll
        for (int n = 0; n < 2; ++n)
#pragma unroll
            for (int jj = 0; jj < 4; ++jj)
                out[(size_t)(row0 + wr * 32 + m * 16 + l16 * 4 + jj) * DOUT
                    + col0 + wc * 32 + n * 16 + l15] = acc[m][n][jj];
}

extern "C" void kernel_launch(void* const* d_in, const int* in_sizes, int n_in,
                              void* d_out, int out_size, void* d_ws, size_t ws_size,
                              hipStream_t stream) {
    const float* x      = (const float*)d_in[0];   // (4,1024,1024)
    const float* weight = (const float*)d_in[1];   // (1024,1024)
    const float* gate_w = (const float*)d_in[2];   // (8,1024)
    const float* lora_U = (const float*)d_in[3];   // (8,16,1024)
    const float* lora_V = (const float*)d_in[4];   // (8,1024,16)
    float* out = (float*)d_out;

    char* ws = (char*)d_ws;
    __hip_bfloat16* Xcat = (__hip_bfloat16*)ws;                        // 4096x1152 (9.44 MB)
    __hip_bfloat16* Ucat = (__hip_bfloat16*)(ws + 9437184);            // 192x1024  (0.39 MB)
    __hip_bfloat16* Wcat = (__hip_bfloat16*)(ws + 9437184 + 393216);   // 1024x1152 (2.36 MB)

    k_cvtuw<<<672, 256, 0, stream>>>(lora_U, gate_w, weight, lora_V, Ucat, Wcat);
    k_gemm1f<<<256, 256, 0, stream>>>(x, Ucat, Xcat);
    k_gemm2<<<1024, 256, 0, stream>>>(Xcat, Wcat, out);
}

// Round 9
// 41.130 us; speedup vs baseline: 1.3468x; 1.0635x over previous
//
#include <hip/hip_runtime.h>
#include <hip/hip_bf16.h>

typedef __attribute__((ext_vector_type(8))) short short8;
typedef __attribute__((ext_vector_type(4))) float f32x4;

#define NTOK 4096
#define DIN  1024
#define DOUT 1024
#define KTOT 1152   // 1024 (W) + 128 (LoRA)
#define XLD  1152
#define TLDS 200    // Tsm leading dim (f32)

__device__ __forceinline__ unsigned short f2bf(float f) {
    __hip_bfloat16 h = __float2bfloat16(f);
    return __builtin_bit_cast(unsigned short, h);
}

__device__ __forceinline__ void gload16(const void* g, void* l) {
    __builtin_amdgcn_global_load_lds((const __attribute__((address_space(1))) void*)g,
                                     (__attribute__((address_space(3))) void*)l, 16, 0, 0);
}

__device__ __forceinline__ uint4 pack2(float4 v0, float4 v1) {
    union { unsigned short u[8]; uint4 q; } pk;
    pk.u[0] = f2bf(v0.x); pk.u[1] = f2bf(v0.y); pk.u[2] = f2bf(v0.z); pk.u[3] = f2bf(v0.w);
    pk.u[4] = f2bf(v1.x); pk.u[5] = f2bf(v1.y); pk.u[6] = f2bf(v1.z); pk.u[7] = f2bf(v1.w);
    return pk.q;
}

__device__ __forceinline__ uint4 pack8(const float* s) {
    return pack2(*(const float4*)s, *(const float4*)(s + 4));
}

// ---- weight prep: Ucat (192x1024) = [lora_U;gate_w;0], Wcat (1024x1152) = [W|V2]
__global__ __launch_bounds__(256) void k_cvtuw(const float* __restrict__ lora_U,
                                               const float* __restrict__ gate_w,
                                               const float* __restrict__ w,
                                               const float* __restrict__ lora_V,
                                               __hip_bfloat16* __restrict__ Ucat,
                                               __hip_bfloat16* __restrict__ Wcat) {
    int b = blockIdx.x;
    if (b < 96) {
        int idx = b * 256 + threadIdx.x;          // 192 rows x 128 groups
        int r = idx >> 7, g = idx & 127;
        uint4 q = make_uint4(0u, 0u, 0u, 0u);
        if (r < 128)      q = pack8(lora_U + (size_t)r * DIN + g * 8);
        else if (r < 136) q = pack8(gate_w + (size_t)(r - 128) * DIN + g * 8);
        *(uint4*)(Ucat + (size_t)r * DIN + g * 8) = q;
    } else {
        int idx = (b - 96) * 256 + threadIdx.x;   // 1024 rows x 144 groups
        int o = idx / 144, g = idx - o * 144;
        const float* s;
        if (g < 128) s = w + (size_t)o * DIN + g * 8;
        else {
            int i0 = (g - 128) * 8;               // 0..127 in LoRA cols
            int e = i0 >> 4, r = i0 & 15;         // r in {0,8}
            s = lora_V + (size_t)e * (DOUT * 16) + (size_t)o * 16 + r;
        }
        *(uint4*)(Wcat + (size_t)o * KTOT + g * 8) = pack8(s);
    }
}

// ---- GEMM1 fused: T = x @ Ucat^T (K=1024), softmax gate, coef -> Xcat ------
// BM=16, BN=192, BK=64, 256 threads = 4 waves, wave tile 16x48, grid 256.
// 2-phase prefetch: double-buffered LDS, STAGE(kt+1) issued before compute(kt).
__global__ __launch_bounds__(256) void k_gemm1f(const float* __restrict__ x,
                                                const __hip_bfloat16* __restrict__ Ucat,
                                                __hip_bfloat16* __restrict__ Xcat) {
    __shared__ char smem[53248];                   // A: 2x2KB @0; B: 2x24KB @4096
    float (*Tsm)[TLDS] = (float(*)[TLDS])smem;     // 12.8KB reuse after loop

    const int t = threadIdx.x, lane = t & 63, wid = t >> 6;
    const int row0 = blockIdx.x * 16;
    const int l7 = lane & 7, l8 = lane >> 3, l15 = lane & 15, l16 = lane >> 4;
    const int scol = ((l7 ^ l8) << 3);             // pre-swizzled global col (B)

    f32x4 acc[3];
#pragma unroll
    for (int n = 0; n < 3; ++n) acc[n] = (f32x4){0.f, 0.f, 0.f, 0.f};

    const int ar = (t & 127) >> 3;                 // A-staging row 0..15
    const int ac8 = (t & 7) * 8;                   // A-staging col group
    const int abyte = ar * 128 + (((t & 7) ^ (ar & 7)) << 4);   // swizzled LDS slot

    int boff[3];
#pragma unroll
    for (int n = 0; n < 3; ++n) boff[n] = (wid * 48 + n * 16 + l15) * 128;
    const int aoff = l15 * 128;
    int sw[2];
#pragma unroll
    for (int ks = 0; ks < 2; ++ks) sw[ks] = (((ks * 4 + l16) ^ l7) << 4);

    // prologue: stage kt=0 into buf0
    if (t < 128) {
        uint4 q = pack8(x + (size_t)(row0 + ar) * DIN + 0 + ac8);
        *(uint4*)(smem + 0 * 2048 + abyte) = q;
        *(uint4*)(Xcat + (size_t)(row0 + ar) * XLD + 0 + ac8) = q;
    }
#pragma unroll
    for (int i = 0; i < 6; ++i) {
        int cj = wid * 6 + i;
        gload16(Ucat + (size_t)(cj * 8 + l8) * DIN + 0 + scol,
                smem + 4096 + cj * 1024);
    }
    __syncthreads();

    int cur = 0;
    for (int kt = 0; kt < 16; ++kt) {
        const bool hasNext = kt < 15;
        const int k1 = (kt + 1) << 6;
        float4 f0, f1;
        if (hasNext && t < 128) {                  // T14: issue x loads early
            const float* s = x + (size_t)(row0 + ar) * DIN + k1 + ac8;
            f0 = *(const float4*)s; f1 = *(const float4*)(s + 4);
        }
        if (hasNext) {                             // prefetch B for kt+1
#pragma unroll
            for (int i = 0; i < 6; ++i) {
                int cj = wid * 6 + i;
                gload16(Ucat + (size_t)(cj * 8 + l8) * DIN + k1 + scol,
                        smem + 4096 + (cur ^ 1) * 24576 + cj * 1024);
            }
        }
        // compute from buf[cur]
        const char* Ab = smem + cur * 2048;
        const char* Bb = smem + 4096 + cur * 24576;
#pragma unroll
        for (int ks = 0; ks < 2; ++ks) {
            short8 af = *(const short8*)(Ab + aoff + sw[ks]);
#pragma unroll
            for (int n = 0; n < 3; ++n) {
                short8 bf = *(const short8*)(Bb + boff[n] + sw[ks]);
                acc[n] = __builtin_amdgcn_mfma_f32_16x16x32_bf16(af, bf, acc[n], 0, 0, 0);
            }
        }
        if (hasNext && t < 128) {                  // convert + ds_write late
            uint4 q = pack2(f0, f1);
            *(uint4*)(smem + (cur ^ 1) * 2048 + abyte) = q;
            *(uint4*)(Xcat + (size_t)(row0 + ar) * XLD + k1 + ac8) = q;
        }
        __syncthreads();
        cur ^= 1;
    }

    // acc -> Tsm (f32), C/D mapping col=lane&15, row=(lane>>4)*4+j
#pragma unroll
    for (int n = 0; n < 3; ++n)
#pragma unroll
        for (int j = 0; j < 4; ++j)
            Tsm[l16 * 4 + j][wid * 48 + n * 16 + l15] = acc[n][j];
    __syncthreads();

    // softmax + coef: 8 threads per token (16 tokens x 8 experts)
    if (t < 128) {
        const int tok = t >> 3, e = t & 7;
        float l[8];
#pragma unroll
        for (int i = 0; i < 8; ++i) l[i] = Tsm[tok][128 + i];
        float m = l[0];
#pragma unroll
        for (int i = 1; i < 8; ++i) m = fmaxf(m, l[i]);
        float s = 0.f;
#pragma unroll
        for (int i = 0; i < 8; ++i) s += __expf(l[i] - m);
        const float g = __expf(l[e] - m) / s * 0.0625f;   // gate * 1/R
        union { unsigned short u[16]; uint4 q[2]; } pk;
#pragma unroll
        for (int jj = 0; jj < 16; ++jj) pk.u[jj] = f2bf(g * Tsm[tok][e * 16 + jj]);
        uint4* dst = (uint4*)(Xcat + (size_t)(row0 + tok) * XLD + 1024 + e * 16);
        dst[0] = pk.q[0]; dst[1] = pk.q[1];
    }
}

// ---- GEMM2: out = Xcat @ Wcat^T (K=1152) -----------------------------------
// BM=128, BN=64, BK=64, 256 threads = 4 waves (2x2), wave tile 64x32.
// 2-phase prefetch dbuf (48KB -> 2 blocks/CU). Grid 512, XCD-bijective:
// xcd=b&7 owns row-tiles xcd*4..+3 x all 16 col-tiles (per-XCD L2 ~3.5MB).
__global__ __launch_bounds__(256) void k_gemm2(const __hip_bfloat16* __restrict__ A,
                                               const __hip_bfloat16* __restrict__ B,
                                               float* __restrict__ out) {
    __shared__ char smem[49152];                   // A: 2x16KB @0; B: 2x8KB @32768
    const int b = blockIdx.x;
    const int xcd = b & 7, j = b >> 3;
    const int bx = xcd * 4 + (j & 3), by = j >> 2;
    const int row0 = bx * 128, col0 = by * 64;

    const int t = threadIdx.x, lane = t & 63, wid = t >> 6;
    const int wr = wid >> 1, wc = wid & 1;
    const int l7 = lane & 7, l8 = lane >> 3, l15 = lane & 15, l16 = lane >> 4;
    const int scol = ((l7 ^ l8) << 3);

    f32x4 zf = {0.f, 0.f, 0.f, 0.f};
    f32x4 acc[4][2];
#pragma unroll
    for (int m = 0; m < 4; ++m)
#pragma unroll
        for (int n = 0; n < 2; ++n) acc[m][n] = zf;

    int aoff[4], boff[2], sw[2];
#pragma unroll
    for (int m = 0; m < 4; ++m) aoff[m] = (wr * 64 + m * 16 + l15) * 128;
#pragma unroll
    for (int n = 0; n < 2; ++n) boff[n] = (wc * 32 + n * 16 + l15) * 128;
#pragma unroll
    for (int ks = 0; ks < 2; ++ks) sw[ks] = (((ks * 4 + l16) ^ l7) << 4);

#define G2_STAGE(buf, kt)                                                      \
    {                                                                          \
        const int k0_ = (kt) << 6;                                             \
        _Pragma("unroll")                                                      \
        for (int i = 0; i < 4; ++i) {                                          \
            int ci = wid * 4 + i;                                              \
            gload16(A + (size_t)(row0 + ci * 8 + l8) * XLD + k0_ + scol,       \
                    smem + (buf) * 16384 + ci * 1024);                         \
        }                                                                      \
        _Pragma("unroll")                                                      \
        for (int i = 0; i < 2; ++i) {                                          \
            int cj = wid * 2 + i;                                              \
            gload16(B + (size_t)(col0 + cj * 8 + l8) * KTOT + k0_ + scol,      \
                    smem + 32768 + (buf) * 8192 + cj * 1024);                  \
        }                                                                      \
    }

#define G2_COMP(buf)                                                           \
    {                                                                          \
        const char* Ab = smem + (buf) * 16384;                                 \
        const char* Bb = smem + 32768 + (buf) * 8192;                          \
        _Pragma("unroll")                                                      \
        for (int ks = 0; ks < 2; ++ks) {                                       \
            short8 af[4], bf[2];                                               \
            _Pragma("unroll")                                                  \
            for (int m = 0; m < 4; ++m)                                        \
                af[m] = *(const short8*)(Ab + aoff[m] + sw[ks]);               \
            _Pragma("unroll")                                                  \
            for (int n = 0; n < 2; ++n)                                        \
                bf[n] = *(const short8*)(Bb + boff[n] + sw[ks]);               \
            _Pragma("unroll")                                                  \
            for (int m = 0; m < 4; ++m)                                        \
                _Pragma("unroll")                                              \
                for (int n = 0; n < 2; ++n)                                    \
                    acc[m][n] = __builtin_amdgcn_mfma_f32_16x16x32_bf16(       \
                        af[m], bf[n], acc[m][n], 0, 0, 0);                     \
        }                                                                      \
    }

    G2_STAGE(0, 0);
    __syncthreads();
    int cur = 0;
    for (int kt = 0; kt < 17; ++kt) {
        G2_STAGE(cur ^ 1, kt + 1);     // prefetch next K-tile
        G2_COMP(cur);                  // compute current (loads fly underneath)
        __syncthreads();               // drain new loads + barrier
        cur ^= 1;
    }
    G2_COMP(cur);                      // epilogue K-tile 17

#pragma unroll
    for (int m = 0; m < 4; ++m)
#pragma unroll
        for (int n = 0; n < 2; ++n)
#pragma unroll
            for (int jj = 0; jj < 4; ++jj)
                out[(size_t)(row0 + wr * 64 + m * 16 + l16 * 4 + jj) * DOUT
                    + col0 + wc * 32 + n * 16 + l15] = acc[m][n][jj];
#undef G2_STAGE
#undef G2_COMP
}

extern "C" void kernel_launch(void* const* d_in, const int* in_sizes, int n_in,
                              void* d_out, int out_size, void* d_ws, size_t ws_size,
                              hipStream_t stream) {
    const float* x      = (const float*)d_in[0];   // (4,1024,1024)
    const float* weight = (const float*)d_in[1];   // (1024,1024)
    const float* gate_w = (const float*)d_in[2];   // (8,1024)
    const float* lora_U = (const float*)d_in[3];   // (8,16,1024)
    const float* lora_V = (const float*)d_in[4];   // (8,1024,16)
    float* out = (float*)d_out;

    char* ws = (char*)d_ws;
    __hip_bfloat16* Xcat = (__hip_bfloat16*)ws;                        // 4096x1152 (9.44 MB)
    __hip_bfloat16* Ucat = (__hip_bfloat16*)(ws + 9437184);            // 192x1024  (0.39 MB)
    __hip_bfloat16* Wcat = (__hip_bfloat16*)(ws + 9437184 + 393216);   // 1024x1152 (2.36 MB)

    k_cvtuw<<<672, 256, 0, stream>>>(lora_U, gate_w, weight, lora_V, Ucat, Wcat);
    k_gemm1f<<<256, 256, 0, stream>>>(x, Ucat, Xcat);
    k_gemm2<<<512, 256, 0, stream>>>(Xcat, Wcat, out);
}